// Round 1
// baseline (596.930 us; speedup 1.0000x reference)
//
#include <hip/hip_runtime.h>

// Problem: x (16,8,512,512) fp32. Per (b,c) row of 2^18 elements compute 1%/99%
// linear-interp quantiles, th = i1+(i99-i1)*alpha, gate = sigmoid(beta/th_new*(|x|-th*mask)),
// out = relu(x)*gate.

#define ROWS 128
#define NPR  262144      // elements per row = 2^18
#define BINS 8192        // top-13 bits of sortable key
#define SHIFT 19         // 32 - 13
#define CAP  4096        // candidate buffer per (row, quantile)
#define TPB  256
#define BPR  16          // blocks per row for full-read kernels

// ws layout in uint32 units
#define H1 (ROWS*BINS)            // hist end -> range info
#define C0 (H1 + ROWS*8)          // counters
#define D0 (C0 + ROWS*2)          // candidate keys
#define Q0 (D0 + ROWS*2*CAP)      // qvals (float, 2 per row)

__device__ __forceinline__ unsigned keyOf(float f) {
    unsigned u = __float_as_uint(f);
    return (u & 0x80000000u) ? ~u : (u | 0x80000000u);
}
__device__ __forceinline__ float keyToFloat(unsigned k) {
    unsigned u = (k & 0x80000000u) ? (k & 0x7fffffffu) : ~k;
    return __uint_as_float(u);
}

__global__ __launch_bounds__(TPB) void k_hist(const float* __restrict__ x,
                                              unsigned* __restrict__ ws) {
    __shared__ unsigned lh[BINS];
    for (int i = threadIdx.x; i < BINS; i += TPB) lh[i] = 0;
    __syncthreads();
    int row = blockIdx.x >> 4;
    int blk = blockIdx.x & 15;
    const float4* xr = (const float4*)(x + (size_t)row * NPR + (size_t)blk * (NPR / BPR));
    const int NV = NPR / BPR / 4;  // 4096 float4 per block
    for (int i = threadIdx.x; i < NV; i += TPB) {
        float4 v = xr[i];
        atomicAdd(&lh[keyOf(v.x) >> SHIFT], 1u);
        atomicAdd(&lh[keyOf(v.y) >> SHIFT], 1u);
        atomicAdd(&lh[keyOf(v.z) >> SHIFT], 1u);
        atomicAdd(&lh[keyOf(v.w) >> SHIFT], 1u);
    }
    __syncthreads();
    unsigned* gh = ws + (size_t)row * BINS;
    for (int i = threadIdx.x; i < BINS; i += TPB) {
        unsigned c = lh[i];
        if (c) atomicAdd(&gh[i], c);
    }
}

__global__ __launch_bounds__(TPB) void k_scan(unsigned* __restrict__ ws) {
    int row = blockIdx.x;
    const unsigned* h = ws + (size_t)row * BINS;
    __shared__ unsigned part[TPB];
    __shared__ unsigned resBin[4], resCb[4];
    const int CH = BINS / TPB;  // 32 bins per thread
    int base = threadIdx.x * CH;
    unsigned s = 0;
    for (int i = 0; i < CH; ++i) s += h[base + i];
    part[threadIdx.x] = s;
    __syncthreads();
    if (threadIdx.x == 0) {
        unsigned run = 0;
        for (int t = 0; t < TPB; ++t) { unsigned tmp = part[t]; part[t] = run; run += tmp; }
    }
    __syncthreads();
    unsigned cum = part[threadIdx.x];
    const unsigned targets[4] = {2621u, 2622u, 259521u, 259522u};
    for (int i = 0; i < CH; ++i) {
        unsigned c = h[base + i];
        #pragma unroll
        for (int t = 0; t < 4; ++t) {
            if (targets[t] >= cum && targets[t] < cum + c) {
                resBin[t] = (unsigned)(base + i);
                resCb[t]  = cum;
            }
        }
        cum += c;
    }
    __syncthreads();
    if (threadIdx.x == 0) {
        unsigned* r = ws + H1 + (size_t)row * 8;
        r[0] = resBin[0]; r[1] = resBin[1]; r[2] = resCb[0];
        r[3] = resBin[2]; r[4] = resBin[3]; r[5] = resCb[2];
    }
}

__global__ __launch_bounds__(TPB) void k_collect(const float* __restrict__ x,
                                                 unsigned* __restrict__ ws) {
    int row = blockIdx.x >> 4;
    int blk = blockIdx.x & 15;
    const unsigned* r = ws + H1 + (size_t)row * 8;
    unsigned blo0 = r[0], bhi0 = r[1], blo1 = r[3], bhi1 = r[4];
    unsigned* cnt   = ws + C0 + (size_t)row * 2;
    unsigned* cand0 = ws + D0 + (size_t)(row * 2) * CAP;
    unsigned* cand1 = cand0 + CAP;
    const float4* xr = (const float4*)(x + (size_t)row * NPR + (size_t)blk * (NPR / BPR));
    const int NV = NPR / BPR / 4;
    for (int i = threadIdx.x; i < NV; i += TPB) {
        float4 v = xr[i];
        float vv[4] = {v.x, v.y, v.z, v.w};
        #pragma unroll
        for (int j = 0; j < 4; ++j) {
            unsigned key = keyOf(vv[j]);
            unsigned bin = key >> SHIFT;
            if (bin >= blo0 && bin <= bhi0) {
                unsigned p = atomicAdd(&cnt[0], 1u);
                if (p < CAP) cand0[p] = key;
            }
            if (bin >= blo1 && bin <= bhi1) {
                unsigned p = atomicAdd(&cnt[1], 1u);
                if (p < CAP) cand1[p] = key;
            }
        }
    }
}

__global__ __launch_bounds__(TPB) void k_select(unsigned* __restrict__ ws) {
    int rq  = blockIdx.x;        // row*2 + iq
    int row = rq >> 1;
    int iq  = rq & 1;
    unsigned m = ws[C0 + rq];
    if (m > CAP) m = CAP;
    __shared__ unsigned keys[CAP];
    const unsigned* cand = ws + D0 + (size_t)rq * CAP;
    for (int i = threadIdx.x; i < CAP; i += TPB)
        keys[i] = (i < (int)m) ? cand[i] : 0xFFFFFFFFu;
    __syncthreads();
    // bitonic sort of CAP elements
    for (int k = 2; k <= CAP; k <<= 1) {
        for (int j = k >> 1; j > 0; j >>= 1) {
            for (int t = threadIdx.x; t < CAP / 2; t += TPB) {
                int i   = ((t & ~(j - 1)) << 1) | (t & (j - 1));
                int ixj = i | j;
                bool up = ((i & k) == 0);
                unsigned a = keys[i], b = keys[ixj];
                if ((a > b) == up) { keys[i] = b; keys[ixj] = a; }
            }
            __syncthreads();
        }
    }
    if (threadIdx.x == 0) {
        const unsigned* r = ws + H1 + (size_t)row * 8;
        unsigned cb = iq ? r[5] : r[2];
        unsigned k  = iq ? 259521u : 2621u;
        double frac = iq ? (0.99 * (double)(NPR - 1) - 259521.0)
                         : (0.01 * (double)(NPR - 1) - 2621.0);
        float vlo = keyToFloat(keys[k - cb]);
        float vhi = keyToFloat(keys[k - cb + 1]);
        float* qv = (float*)(ws + Q0);
        qv[rq] = (float)((double)vlo + ((double)vhi - (double)vlo) * frac);
    }
}

__global__ __launch_bounds__(TPB) void k_out(const float* __restrict__ x,
                                             const float* __restrict__ alpha,
                                             const float* __restrict__ beta,
                                             const unsigned* __restrict__ ws,
                                             float* __restrict__ out) {
    const float* qv = (const float*)(ws + Q0);
    float a  = alpha[0];
    float bt = beta[0];
    const int nvec = ROWS * (NPR / 4);  // 8388608 float4
    int stride = gridDim.x * blockDim.x;
    for (int i = blockIdx.x * blockDim.x + threadIdx.x; i < nvec; i += stride) {
        int row = i >> 16;  // (i*4) >> 18
        float q0 = qv[row * 2], q1 = qv[row * 2 + 1];
        float th = q0 + (q1 - q0) * a;
        bool  msk = th > 1e-14f;
        float thn = msk ? th : 1.0f;
        float scale = bt / thn;
        float thm = msk ? th : 0.0f;
        float4 v = ((const float4*)x)[i];
        float4 o;
        o.x = v.x > 0.f ? v.x / (1.f + __expf(-(scale * (fabsf(v.x) - thm)))) : 0.f;
        o.y = v.y > 0.f ? v.y / (1.f + __expf(-(scale * (fabsf(v.y) - thm)))) : 0.f;
        o.z = v.z > 0.f ? v.z / (1.f + __expf(-(scale * (fabsf(v.z) - thm)))) : 0.f;
        o.w = v.w > 0.f ? v.w / (1.f + __expf(-(scale * (fabsf(v.w) - thm)))) : 0.f;
        ((float4*)out)[i] = o;
    }
}

extern "C" void kernel_launch(void* const* d_in, const int* in_sizes, int n_in,
                              void* d_out, int out_size, void* d_ws, size_t ws_size,
                              hipStream_t stream) {
    const float* x     = (const float*)d_in[0];
    const float* alpha = (const float*)d_in[1];
    const float* beta  = (const float*)d_in[2];
    float* out = (float*)d_out;
    unsigned* ws = (unsigned*)d_ws;
    // zero hist + range info + counters (ws is poisoned 0xAA before every call)
    hipMemsetAsync(ws, 0, (size_t)(C0 + ROWS * 2) * sizeof(unsigned), stream);
    k_hist   <<<ROWS * BPR, TPB, 0, stream>>>(x, ws);
    k_scan   <<<ROWS,       TPB, 0, stream>>>(ws);
    k_collect<<<ROWS * BPR, TPB, 0, stream>>>(x, ws);
    k_select <<<ROWS * 2,   TPB, 0, stream>>>(ws);
    k_out    <<<2048,       TPB, 0, stream>>>(x, alpha, beta, ws, out);
}

// Round 2
// 419.387 us; speedup vs baseline: 1.4233x; 1.4233x over previous
//
#include <hip/hip_runtime.h>

// x (16,8,512,512) fp32. Per (b,c) row of 2^18 elems: 1%/99% linear-interp
// quantiles -> th = i1+(i99-i1)*alpha; out = relu(x)*sigmoid(beta/th_new*(|x|-th*mask)).
//
// R2 design: ONE BLOCK PER ROW fused quantile kernel (hist -> scan -> collect
// -> radix-select, all in LDS, zero global atomics), then a full-grid
// elementwise output kernel. ws holds only qv[256] floats.

#define ROWS 128
#define NPR  262144      // 2^18 elements per row
#define BINS 8192        // top-13 bits of sortable key
#define SHIFT 19
#define CAP  4096        // candidate cap per (row, quantile); Gaussian ~2.6k worst
#define QTPB 1024
#define OTPB 256

// rank targets: q*(n-1) = 0.01*262143 = 2621.43 ; 0.99*262143 = 259521.57
#define K_LO 2621u
#define K_HI 259521u

__device__ __forceinline__ unsigned keyOf(float f) {
    unsigned u = __float_as_uint(f);
    return (u & 0x80000000u) ? ~u : (u | 0x80000000u);
}
__device__ __forceinline__ float keyToFloat(unsigned k) {
    unsigned u = (k & 0x80000000u) ? (k & 0x7fffffffu) : ~k;
    return __uint_as_float(u);
}

__global__ __launch_bounds__(QTPB) void k_quant(const float* __restrict__ x,
                                                float* __restrict__ qv) {
    const int row = blockIdx.x;
    const int tid = threadIdx.x;
    const float4* xr = (const float4*)(x + (size_t)row * NPR);

    // hist (phase 1-2) and cand (phase 3+) alias the same 32 KB
    __shared__ unsigned smem[BINS];
    unsigned* hist = smem;
    unsigned (*cand)[CAP] = (unsigned(*)[CAP])smem;
    __shared__ unsigned part[256];
    __shared__ unsigned sh[256];     // radix-select histogram
    __shared__ unsigned sb[8];       // blo0,bhi0,cb0, blo1,bhi1,cb1
    __shared__ unsigned svar[4];     // select scratch: byte, cumBelow, cntEq, minAbove
    __shared__ unsigned ccnt[2];

    for (int i = tid; i < BINS; i += QTPB) hist[i] = 0;
    __syncthreads();

    // ---- phase 1: 8192-bin histogram of top-13 key bits ----
    const int NV = NPR / 4;  // 65536 float4
    for (int i = tid; i < NV; i += QTPB) {
        float4 v = xr[i];
        atomicAdd(&hist[keyOf(v.x) >> SHIFT], 1u);
        atomicAdd(&hist[keyOf(v.y) >> SHIFT], 1u);
        atomicAdd(&hist[keyOf(v.z) >> SHIFT], 1u);
        atomicAdd(&hist[keyOf(v.w) >> SHIFT], 1u);
    }
    __syncthreads();

    // ---- phase 2: scan, locate bins holding ranks {2621,2622,259521,259522} ----
    const int CH = BINS / 256;  // 32 bins per thread (threads 0..255)
    if (tid < 256) {
        unsigned s = 0;
        int base = tid * CH;
        for (int i = 0; i < CH; ++i) s += hist[base + i];
        part[tid] = s;
    }
    __syncthreads();
    if (tid == 0) {
        unsigned run = 0;
        for (int t = 0; t < 256; ++t) { unsigned tmp = part[t]; part[t] = run; run += tmp; }
    }
    __syncthreads();
    if (tid < 256) {
        unsigned cum = part[tid];
        int base = tid * CH;
        const unsigned targets[4] = {K_LO, K_LO + 1u, K_HI, K_HI + 1u};
        for (int i = 0; i < CH; ++i) {
            unsigned c = hist[base + i];
            if (c) {
                #pragma unroll
                for (int t = 0; t < 4; ++t) {
                    if (targets[t] >= cum && targets[t] < cum + c) {
                        if      (t == 0) { sb[0] = base + i; sb[2] = cum; }
                        else if (t == 1) { sb[1] = base + i; }
                        else if (t == 2) { sb[3] = base + i; sb[5] = cum; }
                        else             { sb[4] = base + i; }
                    }
                }
            }
            cum += c;
        }
    }
    if (tid < 2) ccnt[tid] = 0;
    __syncthreads();   // sb complete; hist no longer needed -> cand may overwrite

    // ---- phase 3: collect candidate keys (bins in range) into LDS ----
    {
        unsigned blo0 = sb[0], bhi0 = sb[1], blo1 = sb[3], bhi1 = sb[4];
        for (int i = tid; i < NV; i += QTPB) {
            float4 v = xr[i];
            float vv[4] = {v.x, v.y, v.z, v.w};
            #pragma unroll
            for (int j = 0; j < 4; ++j) {
                unsigned key = keyOf(vv[j]);
                unsigned bin = key >> SHIFT;
                if (bin >= blo0 && bin <= bhi0) {
                    unsigned p = atomicAdd(&ccnt[0], 1u);
                    if (p < CAP) cand[0][p] = key;
                }
                if (bin >= blo1 && bin <= bhi1) {
                    unsigned p = atomicAdd(&ccnt[1], 1u);
                    if (p < CAP) cand[1][p] = key;
                }
            }
        }
    }
    __syncthreads();

    // ---- phase 4: 4-pass byte-radix select for ranks t and t+1 ----
    for (int iq = 0; iq < 2; ++iq) {
        unsigned m = ccnt[iq]; if (m > CAP) m = CAP;
        unsigned cb = iq ? sb[5] : sb[2];
        unsigned t_lo = (iq ? K_HI : K_LO) - cb;   // 0-based rank among candidates
        unsigned prefix = 0, trem = t_lo, cntEq = 0;
        for (int p = 3; p >= 0; --p) {
            for (int i = tid; i < 256; i += QTPB) sh[i] = 0;
            __syncthreads();
            for (unsigned i = tid; i < m; i += QTPB) {
                unsigned key = cand[iq][i];
                bool match = (p == 3) || ((key >> ((p + 1) * 8)) == (prefix >> ((p + 1) * 8)));
                if (match) atomicAdd(&sh[(key >> (p * 8)) & 255u], 1u);
            }
            __syncthreads();
            if (tid == 0) {
                unsigned cum = 0;
                for (int b = 0; b < 256; ++b) {
                    unsigned c = sh[b];
                    if (trem >= cum && trem < cum + c) { svar[0] = (unsigned)b; svar[1] = cum; svar[2] = c; break; }
                    cum += c;
                }
            }
            __syncthreads();
            prefix |= svar[0] << (p * 8);
            trem   -= svar[1];
            cntEq   = svar[2];
            __syncthreads();   // protect sh before next pass's zeroing
        }
        unsigned vlo_key = prefix;
        unsigned cntLess = t_lo - trem;      // #keys < vlo
        unsigned vhi_key;
        if (t_lo + 1u < cntLess + cntEq) {
            vhi_key = vlo_key;               // duplicate covers rank t+1
        } else {
            if (tid == 0) svar[3] = 0xFFFFFFFFu;
            __syncthreads();
            for (unsigned i = tid; i < m; i += QTPB) {
                unsigned key = cand[iq][i];
                if (key > vlo_key) atomicMin(&svar[3], key);
            }
            __syncthreads();
            vhi_key = svar[3];
        }
        if (tid == 0) {
            double frac = iq ? (0.99 * (double)(NPR - 1) - (double)K_HI)
                             : (0.01 * (double)(NPR - 1) - (double)K_LO);
            double vlo = (double)keyToFloat(vlo_key);
            double vhi = (double)keyToFloat(vhi_key);
            qv[row * 2 + iq] = (float)(vlo + (vhi - vlo) * frac);
        }
        __syncthreads();
    }
}

__global__ __launch_bounds__(OTPB) void k_out(const float* __restrict__ x,
                                              const float* __restrict__ alpha,
                                              const float* __restrict__ beta,
                                              const float* __restrict__ qv,
                                              float* __restrict__ out) {
    float a  = alpha[0];
    float bt = beta[0];
    const int nvec = ROWS * (NPR / 4);  // 8388608 float4
    int stride = gridDim.x * blockDim.x;
    for (int i = blockIdx.x * blockDim.x + threadIdx.x; i < nvec; i += stride) {
        int row = i >> 16;  // (i*4) >> 18
        float q0 = qv[row * 2], q1 = qv[row * 2 + 1];
        float th = q0 + (q1 - q0) * a;
        bool  msk = th > 1e-14f;
        float thn = msk ? th : 1.0f;
        float scale = bt / thn;
        float thm = msk ? th : 0.0f;
        float4 v = ((const float4*)x)[i];
        float4 o;
        o.x = v.x > 0.f ? v.x / (1.f + __expf(-(scale * (fabsf(v.x) - thm)))) : 0.f;
        o.y = v.y > 0.f ? v.y / (1.f + __expf(-(scale * (fabsf(v.y) - thm)))) : 0.f;
        o.z = v.z > 0.f ? v.z / (1.f + __expf(-(scale * (fabsf(v.z) - thm)))) : 0.f;
        o.w = v.w > 0.f ? v.w / (1.f + __expf(-(scale * (fabsf(v.w) - thm)))) : 0.f;
        ((float4*)out)[i] = o;
    }
}

extern "C" void kernel_launch(void* const* d_in, const int* in_sizes, int n_in,
                              void* d_out, int out_size, void* d_ws, size_t ws_size,
                              hipStream_t stream) {
    const float* x     = (const float*)d_in[0];
    const float* alpha = (const float*)d_in[1];
    const float* beta  = (const float*)d_in[2];
    float* out = (float*)d_out;
    float* qv  = (float*)d_ws;   // 256 floats; written unconditionally, no zeroing
    k_quant<<<ROWS, QTPB, 0, stream>>>(x, qv);
    k_out  <<<2048, OTPB, 0, stream>>>(x, alpha, beta, qv, out);
}